// Round 10
// baseline (283.454 us; speedup 1.0000x reference)
//
#include <hip/hip_runtime.h>
#include <hip/hip_bf16.h>

#define N_NODES 100000
#define N_EDGES 1600000
#define IN_CH 50
#define NPB 256                                   // nodes per bucket (dst >> 8)
#define NB ((N_NODES + NPB - 1) / NPB)            // 391 buckets
#define CAPLOG 13                                 // 8192 slots/bucket (max ~4.5K used)
#define EPB 8192                                  // edges per bin block (8/thread)
#define NBLK_A ((N_EDGES + EPB - 1) / EPB)        // 196 bin blocks
#define PAD_BLOCKS ((N_NODES * 16 + 1023) / 1024) // 1563 pad blocks (4ch/thread)

__device__ __forceinline__ unsigned pack2bf(float a, float b) {
    __hip_bfloat16 lo = __float2bfloat16(a);
    __hip_bfloat16 hi = __float2bfloat16(b);
    return ((unsigned)*(unsigned short*)&hi << 16) | *(unsigned short*)&lo;
}

// ---- 1. bin edges into fixed-capacity buckets (+ extra blocks: pad x->xb bf16) ----
// R9-proven rank-from-count; R10: pad lane does 4 channels/thread (uint2 writes).
__global__ __launch_bounds__(1024) void bin_pad_kernel(
    const int* __restrict__ src, const int* __restrict__ dst,
    int* __restrict__ cursor_rel, unsigned* __restrict__ binned,
    const float* __restrict__ x, unsigned short* __restrict__ xb) {
    if (blockIdx.x >= NBLK_A) {                    // pad lane
        int t = (blockIdx.x - NBLK_A) * 1024 + threadIdx.x;
        if (t >= N_NODES * 16) return;
        int n = t >> 4, q = t & 15;                // q = 4-channel group
        unsigned lo = 0, hi = 0;
        if (q < 12) {
            float2 v0 = *(const float2*)(x + n * IN_CH + q * 4);
            float2 v1 = *(const float2*)(x + n * IN_CH + q * 4 + 2);
            lo = pack2bf(v0.x, v0.y);
            hi = pack2bf(v1.x, v1.y);
        } else if (q == 12) {                      // ch 48,49 live; 50,51 zero
            float2 v0 = *(const float2*)(x + n * IN_CH + 48);
            lo = pack2bf(v0.x, v0.y);
        }
        *(uint2*)(xb + n * 64 + q * 4) = make_uint2(lo, hi);
        return;
    }
    __shared__ int bc[NB];
    __shared__ int boff[NB];
    int t = threadIdx.x;
    if (t < NB) bc[t] = 0;
    __syncthreads();
    int e0 = blockIdx.x * EPB;
    int ne = min(e0 + EPB, N_EDGES) - e0;
    unsigned payl[8];
    int bkt[8], rnk[8];
    #pragma unroll
    for (int r = 0; r < 8; ++r) {
        int i = t + r * 1024;
        if (i < ne) {
            int d = dst[e0 + i];
            payl[r] = ((unsigned)(d & 255) << 17) | (unsigned)src[e0 + i];
            bkt[r]  = d >> 8;
            rnk[r]  = atomicAdd(&bc[bkt[r]], 1);   // rank within bucket, this block
        }
    }
    __syncthreads();
    if (t < NB) {
        int v = bc[t];
        int rel = v ? atomicAdd(&cursor_rel[t], v) : 0;
        boff[t] = (t << CAPLOG) + rel;
    }
    __syncthreads();
    #pragma unroll
    for (int r = 0; r < 8; ++r) {
        int i = t + r * 1024;
        if (i < ne)
            binned[boff[bkt[r]] + rnk[r]] = payl[r];
    }
}

// ---- 2. per-bucket fine sort -> cnt, row_start, csr_src (R9-proven) ----
__global__ __launch_bounds__(1024) void bucket_fine(
    const unsigned* __restrict__ binned, const int* __restrict__ cursor_rel,
    int* __restrict__ cnt, int* __restrict__ row_start, int* __restrict__ csr_src) {
    __shared__ unsigned srt[1 << CAPLOG];          // 32KB
    __shared__ int lcnt[NPB];
    __shared__ int lofs[NPB];
    __shared__ int sc[NPB];
    int t = threadIdx.x;
    int b = blockIdx.x;
    int nbase = b * NPB;
    int bbase = b << CAPLOG;
    int ecnt  = cursor_rel[b];
    if (t < NPB) lcnt[t] = 0;
    __syncthreads();
    unsigned pay[8];
    int rnk[8];
    #pragma unroll
    for (int r = 0; r < 8; ++r) {
        int i = t + r * 1024;
        if (i < ecnt) {
            pay[r] = binned[bbase + i];
            rnk[r] = atomicAdd(&lcnt[(pay[r] >> 17) & 255], 1);
        }
    }
    __syncthreads();
    int v = (t < NPB) ? lcnt[t] : 0;
    if (t < NPB) sc[t] = v;
    __syncthreads();
    for (int off = 1; off < NPB; off <<= 1) {      // Hillis-Steele over 256
        int tmp = (t < NPB && t >= off) ? sc[t - off] : 0;
        __syncthreads();
        if (t < NPB) sc[t] += tmp;
        __syncthreads();
    }
    if (t < NPB) {
        int excl = sc[t] - v;
        lofs[t] = excl;
        int n = nbase + t;
        if (n < N_NODES) { cnt[n] = v; row_start[n] = bbase + excl; }
    }
    __syncthreads();
    #pragma unroll
    for (int r = 0; r < 8; ++r) {
        int i = t + r * 1024;
        if (i < ecnt)
            srt[lofs[(pay[r] >> 17) & 255] + rnk[r]] = pay[r] & 0x1FFFFu;
    }
    __syncthreads();
    for (int i = t; i < ecnt; i += 1024)
        csr_src[bbase + i] = (int)srt[i];          // coalesced
}

// unpack 8 bf16 from uint4, predicated fma into acc[0..8)
__device__ __forceinline__ void upadd8(float* a, uint4 v, float p) {
    a[0] = fmaf(p, __uint_as_float(v.x << 16), a[0]);
    a[1] = fmaf(p, __uint_as_float(v.x & 0xffff0000u), a[1]);
    a[2] = fmaf(p, __uint_as_float(v.y << 16), a[2]);
    a[3] = fmaf(p, __uint_as_float(v.y & 0xffff0000u), a[3]);
    a[4] = fmaf(p, __uint_as_float(v.z << 16), a[4]);
    a[5] = fmaf(p, __uint_as_float(v.z & 0xffff0000u), a[5]);
    a[6] = fmaf(p, __uint_as_float(v.w << 16), a[6]);
    a[7] = fmaf(p, __uint_as_float(v.w & 0xffff0000u), a[7]);
}

// wave-local LDS fence: LDS ops of one wave complete in order; no block barrier.
#define WAVE_LDS_FENCE() __asm__ volatile("s_waitcnt lgkmcnt(0)" ::: "memory")

// Gather-mean of 2 nodes per wave (R10): wave-uniform guards skip dead
// group-loads + their unpack/FMA (deg residues <= 8 make the 2nd group fully
// predicated-off ~50% of the time on chunk>=1). Load->load->fma->fma order kept.
__device__ __forceinline__ void gather2(
    const unsigned short* __restrict__ featb, const int* __restrict__ csr_src,
    const int* __restrict__ row_start, const int* __restrict__ cnt,
    int nb, int lane, float acc[2][8]) {
    int g  = lane >> 3;
    int cw = (lane & 7) * 8;
    int start[2], deg[2], sv[2];
    #pragma unroll
    for (int i = 0; i < 2; ++i) {
        start[i] = row_start[nb + i];
        deg[i]   = cnt[nb + i];
        #pragma unroll
        for (int c = 0; c < 8; ++c) acc[i][c] = 0.f;
    }
    int dmax = max(deg[0], deg[1]);
    #pragma unroll
    for (int i = 0; i < 2; ++i)
        sv[i] = (lane < deg[i]) ? csr_src[start[i] + lane] : 0;

    #pragma unroll
    for (int cb = 0; cb < 64; cb += 16) {
        if (cb >= dmax) break;                 // wave-uniform
        int s00 = __shfl(sv[0], cb + g);
        int s01 = __shfl(sv[0], cb + 8 + g);
        int s10 = __shfl(sv[1], cb + g);
        int s11 = __shfl(sv[1], cb + 8 + g);
        int rem0 = deg[0] - cb;
        int rem1 = deg[1] - cb;
        bool l00 = rem0 > 0, l01 = rem0 > 8;   // wave-uniform guards
        bool l10 = rem1 > 0, l11 = rem1 > 8;
        uint4 v00, v01, v10, v11;
        if (l00) v00 = *(const uint4*)(featb + s00 * 64 + cw);
        if (l01) v01 = *(const uint4*)(featb + s01 * 64 + cw);
        if (l10) v10 = *(const uint4*)(featb + s10 * 64 + cw);
        if (l11) v11 = *(const uint4*)(featb + s11 * 64 + cw);
        if (l00) upadd8(acc[0], v00, (g < rem0) ? 1.f : 0.f);
        if (l01) upadd8(acc[0], v01, (g + 8 < rem0) ? 1.f : 0.f);
        if (l10) upadd8(acc[1], v10, (g < rem1) ? 1.f : 0.f);
        if (l11) upadd8(acc[1], v11, (g + 8 < rem1) ? 1.f : 0.f);
    }
    if (dmax > 64) {                           // rare tail (Poisson(16): ~never)
        for (int i = 0; i < 2; ++i) {
            for (int c0 = 64; c0 < deg[i]; c0 += 64) {
                int rem = deg[i] - c0; if (rem > 64) rem = 64;
                int sx = (lane < rem) ? csr_src[start[i] + c0 + lane] : 0;
                for (int cb = 0; cb < rem; cb += 16) {
                    int s0 = __shfl(sx, cb + g);
                    int s1 = __shfl(sx, cb + 8 + g);
                    float p0 = (cb + g < rem) ? 1.f : 0.f;
                    float p1 = (cb + 8 + g < rem) ? 1.f : 0.f;
                    uint4 v0 = *(const uint4*)(featb + s0 * 64 + cw);
                    uint4 v1 = *(const uint4*)(featb + s1 * 64 + cw);
                    upadd8(acc[i], v0, p0);
                    upadd8(acc[i], v1, p1);
                }
            }
        }
    }
    #pragma unroll
    for (int i = 0; i < 2; ++i) {
        float inv = 1.0f / fmaxf((float)deg[i], 1.0f);
        #pragma unroll
        for (int c = 0; c < 8; ++c) {
            float t = acc[i][c];
            t += __shfl_xor(t, 8);
            t += __shfl_xor(t, 16);
            t += __shfl_xor(t, 32);
            acc[i][c] = t * inv;
        }
    }
}

__device__ __forceinline__ float bf16u(unsigned short u) {
    return __uint_as_float(((unsigned)u) << 16);
}

// ---- 3. layer 1 (R2/R4-proven + R10 guards): gather(xb) + W1 GEMM -> h1b ----
__global__ __launch_bounds__(256, 8) void layer1_fused(
    const unsigned short* __restrict__ xb,
    const int* __restrict__ csr_src, const int* __restrict__ row_start,
    const int* __restrict__ cnt, const float* __restrict__ W1,
    const float* __restrict__ b1, unsigned short* __restrict__ h1b) {
    int wv   = threadIdx.x >> 6;
    int lane = threadIdx.x & 63;
    int nb   = (blockIdx.x * 4 + wv) * 2;      // N_NODES % 8 == 0

    float acc[2][8];
    gather2(xb, csr_src, row_start, cnt, nb, lane, acc);

    __shared__ __align__(16) float selfF[4][2][64];
    __shared__ __align__(16) float meanF[4][2][64];
    #pragma unroll
    for (int i = 0; i < 2; ++i) {
        selfF[wv][i][lane] = bf16u(xb[((nb + i) << 6) + lane]);
        if (lane < 8) {
            *(float4*)&meanF[wv][i][lane * 8] =
                make_float4(acc[i][0], acc[i][1], acc[i][2], acc[i][3]);
            *(float4*)&meanF[wv][i][lane * 8 + 4] =
                make_float4(acc[i][4], acc[i][5], acc[i][6], acc[i][7]);
        }
    }
    WAVE_LDS_FENCE();

    float ao[2];
    float bb = b1[lane];
    #pragma unroll
    for (int i = 0; i < 2; ++i) ao[i] = bb;
    #pragma unroll
    for (int k = 0; k < IN_CH; ++k) {
        float w = W1[k * 64 + lane];           // lanes coalesced, reused x2
        #pragma unroll
        for (int i = 0; i < 2; ++i) ao[i] = fmaf(selfF[wv][i][k], w, ao[i]);
    }
    #pragma unroll
    for (int k = 0; k < IN_CH; ++k) {
        float w = W1[(IN_CH + k) * 64 + lane];
        #pragma unroll
        for (int i = 0; i < 2; ++i) ao[i] = fmaf(meanF[wv][i][k], w, ao[i]);
    }
    #pragma unroll
    for (int i = 0; i < 2; ++i) {
        float r = fmaxf(ao[i], 0.f);
        __hip_bfloat16 hb = __float2bfloat16(r);
        h1b[((nb + i) << 6) + lane] = *(unsigned short*)&hb;
    }
}

// ---- 3b. W2 pre-transform v2 (R5/R6-proven): 4 nodes/wave, all 64 lanes.
__global__ __launch_bounds__(256) void transform_w2(
    const unsigned short* __restrict__ h1b,
    const float* __restrict__ W2, const float* __restrict__ b2,
    unsigned short* __restrict__ y2b, float* __restrict__ yselff) {
    __shared__ __align__(16) float hrowF[4][4][64];    // 16KB: [wave][node][ch]
    int t    = threadIdx.x;
    int wv   = t >> 6;
    int lane = t & 63;
    int nb4  = blockIdx.x * 16 + wv * 4;               // grid*16 == N_NODES

    {
        int in = lane >> 4, q = lane & 15;
        uint2 hv = *(const uint2*)(h1b + (nb4 + in) * 64 + q * 4);
        float4 f;
        f.x = __uint_as_float(hv.x << 16);
        f.y = __uint_as_float(hv.x & 0xffff0000u);
        f.z = __uint_as_float(hv.y << 16);
        f.w = __uint_as_float(hv.y & 0xffff0000u);
        *(float4*)&hrowF[wv][in][q * 4] = f;
    }
    WAVE_LDS_FENCE();

    int jj  = lane & 31;
    int sel = lane >> 5;                               // 0: self (ys), 1: mean (ym)
    const float* Wp = W2 + sel * 64 * 32 + jj;
    float a[4] = {0.f, 0.f, 0.f, 0.f};
    #pragma unroll
    for (int k = 0; k < 64; ++k) {
        float w = Wp[k * 32];                          // 2 coalesced rows / wave
        #pragma unroll
        for (int i = 0; i < 4; ++i)
            a[i] = fmaf(hrowF[wv][i][k], w, a[i]);     // LDS broadcast
    }
    if (sel == 0) {
        float bb = b2[jj];
        #pragma unroll
        for (int i = 0; i < 4; ++i)
            yselff[(nb4 + i) * 32 + jj] = a[i] + bb;
    } else {
        #pragma unroll
        for (int i = 0; i < 4; ++i) {
            __hip_bfloat16 hb = __float2bfloat16(a[i]);
            y2b[(nb4 + i) * 32 + jj] = *(unsigned short*)&hb;
        }
    }
}

// ---- 4. layers 2+3 (R3/R6-proven slim + R10 guards): gather y2b, mean,
//      +yself, ReLU, dot W3.
__global__ __launch_bounds__(256, 8) void layer23_fused(
    const unsigned short* __restrict__ y2b,
    const int* __restrict__ csr_src, const int* __restrict__ row_start,
    const int* __restrict__ cnt, const float* __restrict__ yselff,
    const float* __restrict__ W3, const float* __restrict__ b3,
    float* __restrict__ out) {
    int wv   = threadIdx.x >> 6;
    int lane = threadIdx.x & 63;
    int nb   = (blockIdx.x * 4 + wv) * 2;
    int g  = lane >> 2;                        // 16 groups of 4 lanes
    int cw = (lane & 3) * 8;                   // bf16 offset within 32-ch row

    int start[2], deg[2], sv[2];
    float acc[2][8];
    #pragma unroll
    for (int i = 0; i < 2; ++i) {
        start[i] = row_start[nb + i];
        deg[i]   = cnt[nb + i];
        #pragma unroll
        for (int c = 0; c < 8; ++c) acc[i][c] = 0.f;
    }
    int dmax = max(deg[0], deg[1]);
    #pragma unroll
    for (int i = 0; i < 2; ++i)
        sv[i] = (lane < deg[i]) ? csr_src[start[i] + lane] : 0;

    #pragma unroll
    for (int cb = 0; cb < 64; cb += 32) {      // 32 neighbors per round trip
        if (cb >= dmax) break;                 // wave-uniform
        int s00 = __shfl(sv[0], cb + g);
        int s01 = __shfl(sv[0], cb + 16 + g);
        int s10 = __shfl(sv[1], cb + g);
        int s11 = __shfl(sv[1], cb + 16 + g);
        int rem0 = deg[0] - cb;
        int rem1 = deg[1] - cb;
        bool l00 = rem0 > 0, l01 = rem0 > 16;  // wave-uniform: skip dead group
        bool l10 = rem1 > 0, l11 = rem1 > 16;  // (deg<=16 ~53% on chunk 0)
        uint4 v00, v01, v10, v11;
        if (l00) v00 = *(const uint4*)(y2b + s00 * 32 + cw);
        if (l01) v01 = *(const uint4*)(y2b + s01 * 32 + cw);
        if (l10) v10 = *(const uint4*)(y2b + s10 * 32 + cw);
        if (l11) v11 = *(const uint4*)(y2b + s11 * 32 + cw);
        if (l00) upadd8(acc[0], v00, (g < rem0) ? 1.f : 0.f);
        if (l01) upadd8(acc[0], v01, (g + 16 < rem0) ? 1.f : 0.f);
        if (l10) upadd8(acc[1], v10, (g < rem1) ? 1.f : 0.f);
        if (l11) upadd8(acc[1], v11, (g + 16 < rem1) ? 1.f : 0.f);
    }
    if (dmax > 64) {                           // rare tail
        for (int i = 0; i < 2; ++i) {
            for (int c0 = 64; c0 < deg[i]; c0 += 64) {
                int rem = deg[i] - c0; if (rem > 64) rem = 64;
                int sx = (lane < rem) ? csr_src[start[i] + c0 + lane] : 0;
                for (int cb = 0; cb < rem; cb += 32) {
                    int s0 = __shfl(sx, cb + g);
                    int s1 = __shfl(sx, cb + 16 + g);
                    float p0 = (cb + g < rem) ? 1.f : 0.f;
                    float p1 = (cb + 16 + g < rem) ? 1.f : 0.f;
                    uint4 v0 = *(const uint4*)(y2b + s0 * 32 + cw);
                    uint4 v1 = *(const uint4*)(y2b + s1 * 32 + cw);
                    upadd8(acc[i], v0, p0);
                    upadd8(acc[i], v1, p1);
                }
            }
        }
    }

    // reduce across the 16 groups (lane bits 2..5), apply mean
    __shared__ __align__(16) float aggF[4][2][32];
    #pragma unroll
    for (int i = 0; i < 2; ++i) {
        float inv = 1.0f / fmaxf((float)deg[i], 1.0f);
        #pragma unroll
        for (int c = 0; c < 8; ++c) {
            float t = acc[i][c];
            t += __shfl_xor(t, 4);
            t += __shfl_xor(t, 8);
            t += __shfl_xor(t, 16);
            t += __shfl_xor(t, 32);
            acc[i][c] = t * inv;
        }
    }
    if (lane < 4) {
        #pragma unroll
        for (int i = 0; i < 2; ++i) {
            *(float4*)&aggF[wv][i][lane * 8] =
                make_float4(acc[i][0], acc[i][1], acc[i][2], acc[i][3]);
            *(float4*)&aggF[wv][i][lane * 8 + 4] =
                make_float4(acc[i][4], acc[i][5], acc[i][6], acc[i][7]);
        }
    }
    WAVE_LDS_FENCE();

    int hh = lane >> 5;                        // half-wave id: node nb+hh
    int j  = lane & 31;
    float pre = yselff[(nb + hh) * 32 + j] + aggF[wv][hh][j];
    float v0 = fmaxf(pre, 0.f) * W3[j];
    #pragma unroll
    for (int off = 1; off <= 16; off <<= 1)
        v0 += __shfl_xor(v0, off);
    if (j == 0)
        out[nb + hh] = v0 + b3[0];
}

extern "C" void kernel_launch(void* const* d_in, const int* in_sizes, int n_in,
                              void* d_out, int out_size, void* d_ws, size_t ws_size,
                              hipStream_t stream) {
    const float* x   = (const float*)d_in[0];
    const int*   ei  = (const int*)d_in[1];
    const int*   src = ei;
    const int*   dst = ei + N_EDGES;
    const float* W1  = (const float*)d_in[2];
    const float* b1  = (const float*)d_in[3];
    const float* W2  = (const float*)d_in[4];
    const float* b2  = (const float*)d_in[5];
    const float* W3  = (const float*)d_in[6];
    const float* b3  = (const float*)d_in[7];
    float* out = (float*)d_out;

    // ws (~78 MB): cursor_rel[512] | cnt | row_start | binned 12.8MB | csr_src 12.8MB |
    //   xb bf16 12.8MB | h1b bf16 12.8MB | y2b bf16 6.4MB | yselff fp32 12.8MB
    char* ws = (char*)d_ws;
    auto align = [](size_t v) { return (v + 255) & ~(size_t)255; };
    size_t o = 0;
    int* cursor_rel = (int*)(ws + o); o = align(o + 512 * 4);
    int* cnt       = (int*)(ws + o); o = align(o + (size_t)N_NODES * 4);
    int* row_start = (int*)(ws + o); o = align(o + (size_t)N_NODES * 4);
    unsigned* binned = (unsigned*)(ws + o); o = align(o + ((size_t)NB << CAPLOG) * 4);
    int* csr_src   = (int*)(ws + o); o = align(o + ((size_t)NB << CAPLOG) * 4);
    unsigned short* xb  = (unsigned short*)(ws + o); o = align(o + (size_t)N_NODES * 64 * 2);
    unsigned short* h1b = (unsigned short*)(ws + o); o = align(o + (size_t)N_NODES * 64 * 2);
    unsigned short* y2b = (unsigned short*)(ws + o); o = align(o + (size_t)N_NODES * 32 * 2);
    float* yselff = (float*)(ws + o); o = align(o + (size_t)N_NODES * 32 * 4);

    (void)hipMemsetAsync(cursor_rel, 0, 512 * sizeof(int), stream);

    bin_pad_kernel<<<NBLK_A + PAD_BLOCKS, 1024, 0, stream>>>(src, dst, cursor_rel,
                                                             binned, x, xb);
    bucket_fine<<<NB, 1024, 0, stream>>>(binned, cursor_rel, cnt, row_start, csr_src);

    layer1_fused<<<N_NODES / 8, 256, 0, stream>>>(xb, csr_src, row_start, cnt,
                                                  W1, b1, h1b);
    transform_w2<<<N_NODES / 16, 256, 0, stream>>>(h1b, W2, b2, y2b, yselff);
    layer23_fused<<<N_NODES / 8, 256, 0, stream>>>(y2b, csr_src, row_start, cnt,
                                                   yselff, W3, b3, out);
}

// Round 12
// 224.831 us; speedup vs baseline: 1.2607x; 1.2607x over previous
//
#include <hip/hip_runtime.h>
#include <hip/hip_bf16.h>

#define N_NODES 100000
#define N_EDGES 1600000
#define IN_CH 50
#define NPB 256                                   // nodes per bucket (dst >> 8)
#define NB ((N_NODES + NPB - 1) / NPB)            // 391 buckets
#define CAPLOG 13                                 // 8192 slots/bucket (max ~4.5K used)
#define EPB 8192                                  // edges per bin block (8/thread)
#define NBLK_A ((N_EDGES + EPB - 1) / EPB)        // 196 bin blocks
#define PAD_BLOCKS ((N_NODES * 16 + 1023) / 1024) // 1563 pad blocks (4ch/thread)

__device__ __forceinline__ unsigned pack2bf(float a, float b) {
    __hip_bfloat16 lo = __float2bfloat16(a);
    __hip_bfloat16 hi = __float2bfloat16(b);
    return ((unsigned)*(unsigned short*)&hi << 16) | *(unsigned short*)&lo;
}

// ---- 1. bin edges into fixed-capacity buckets (+ extra blocks: pad x->xb bf16) ----
// R9-proven rank-from-count; pad lane 4 channels/thread (uint2 writes, R10-run).
__global__ __launch_bounds__(1024) void bin_pad_kernel(
    const int* __restrict__ src, const int* __restrict__ dst,
    int* __restrict__ cursor_rel, unsigned* __restrict__ binned,
    const float* __restrict__ x, unsigned short* __restrict__ xb) {
    if (blockIdx.x >= NBLK_A) {                    // pad lane
        int t = (blockIdx.x - NBLK_A) * 1024 + threadIdx.x;
        if (t >= N_NODES * 16) return;
        int n = t >> 4, q = t & 15;                // q = 4-channel group
        unsigned lo = 0, hi = 0;
        if (q < 12) {
            float2 v0 = *(const float2*)(x + n * IN_CH + q * 4);
            float2 v1 = *(const float2*)(x + n * IN_CH + q * 4 + 2);
            lo = pack2bf(v0.x, v0.y);
            hi = pack2bf(v1.x, v1.y);
        } else if (q == 12) {                      // ch 48,49 live; 50,51 zero
            float2 v0 = *(const float2*)(x + n * IN_CH + 48);
            lo = pack2bf(v0.x, v0.y);
        }
        *(uint2*)(xb + n * 64 + q * 4) = make_uint2(lo, hi);
        return;
    }
    __shared__ int bc[NB];
    __shared__ int boff[NB];
    int t = threadIdx.x;
    if (t < NB) bc[t] = 0;
    __syncthreads();
    int e0 = blockIdx.x * EPB;
    int ne = min(e0 + EPB, N_EDGES) - e0;
    unsigned payl[8];
    int bkt[8], rnk[8];
    #pragma unroll
    for (int r = 0; r < 8; ++r) {
        int i = t + r * 1024;
        if (i < ne) {
            int d = dst[e0 + i];
            payl[r] = ((unsigned)(d & 255) << 17) | (unsigned)src[e0 + i];
            bkt[r]  = d >> 8;
            rnk[r]  = atomicAdd(&bc[bkt[r]], 1);   // rank within bucket, this block
        }
    }
    __syncthreads();
    if (t < NB) {
        int v = bc[t];
        int rel = v ? atomicAdd(&cursor_rel[t], v) : 0;
        boff[t] = (t << CAPLOG) + rel;
    }
    __syncthreads();
    #pragma unroll
    for (int r = 0; r < 8; ++r) {
        int i = t + r * 1024;
        if (i < ne)
            binned[boff[bkt[r]] + rnk[r]] = payl[r];
    }
}

// ---- 2. per-bucket fine sort -> cnt, row_start, csr_src (exact R9-proven) ----
__global__ __launch_bounds__(1024) void bucket_fine(
    const unsigned* __restrict__ binned, const int* __restrict__ cursor_rel,
    int* __restrict__ cnt, int* __restrict__ row_start, int* __restrict__ csr_src) {
    __shared__ unsigned srt[1 << CAPLOG];          // 32KB
    __shared__ int lcnt[NPB];
    __shared__ int lofs[NPB];
    __shared__ int sc[NPB];
    int t = threadIdx.x;
    int b = blockIdx.x;
    int nbase = b * NPB;
    int bbase = b << CAPLOG;
    int ecnt  = cursor_rel[b];
    if (t < NPB) lcnt[t] = 0;
    __syncthreads();
    unsigned pay[8];
    int rnk[8];
    #pragma unroll
    for (int r = 0; r < 8; ++r) {
        int i = t + r * 1024;
        if (i < ecnt) {
            pay[r] = binned[bbase + i];
            rnk[r] = atomicAdd(&lcnt[(pay[r] >> 17) & 255], 1);
        }
    }
    __syncthreads();
    int v = (t < NPB) ? lcnt[t] : 0;
    if (t < NPB) sc[t] = v;
    __syncthreads();
    for (int off = 1; off < NPB; off <<= 1) {      // Hillis-Steele over 256
        int tmp = (t < NPB && t >= off) ? sc[t - off] : 0;
        __syncthreads();
        if (t < NPB) sc[t] += tmp;
        __syncthreads();
    }
    if (t < NPB) {
        int excl = sc[t] - v;
        lofs[t] = excl;
        int n = nbase + t;
        if (n < N_NODES) { cnt[n] = v; row_start[n] = bbase + excl; }
    }
    __syncthreads();
    #pragma unroll
    for (int r = 0; r < 8; ++r) {
        int i = t + r * 1024;
        if (i < ecnt)
            srt[lofs[(pay[r] >> 17) & 255] + rnk[r]] = pay[r] & 0x1FFFFu;
    }
    __syncthreads();
    for (int i = t; i < ecnt; i += 1024)
        csr_src[bbase + i] = (int)srt[i];          // coalesced
}

// unpack 8 bf16 from uint4, predicated fma into acc[0..8)
__device__ __forceinline__ void upadd8(float* a, uint4 v, float p) {
    a[0] = fmaf(p, __uint_as_float(v.x << 16), a[0]);
    a[1] = fmaf(p, __uint_as_float(v.x & 0xffff0000u), a[1]);
    a[2] = fmaf(p, __uint_as_float(v.y << 16), a[2]);
    a[3] = fmaf(p, __uint_as_float(v.y & 0xffff0000u), a[3]);
    a[4] = fmaf(p, __uint_as_float(v.z << 16), a[4]);
    a[5] = fmaf(p, __uint_as_float(v.z & 0xffff0000u), a[5]);
    a[6] = fmaf(p, __uint_as_float(v.w << 16), a[6]);
    a[7] = fmaf(p, __uint_as_float(v.w & 0xffff0000u), a[7]);
}

// wave-local LDS fence: LDS ops of one wave complete in order; no block barrier.
#define WAVE_LDS_FENCE() __asm__ volatile("s_waitcnt lgkmcnt(0)" ::: "memory")

// Gather-mean of 2 nodes per wave (exact R9: unconditional loads — R10's
// conditional uint4 assignment spilled to scratch, +137MB HBM writes).
__device__ __forceinline__ void gather2(
    const unsigned short* __restrict__ featb, const int* __restrict__ csr_src,
    const int* __restrict__ row_start, const int* __restrict__ cnt,
    int nb, int lane, float acc[2][8]) {
    int g  = lane >> 3;
    int cw = (lane & 7) * 8;
    int start[2], deg[2], sv[2];
    #pragma unroll
    for (int i = 0; i < 2; ++i) {
        start[i] = row_start[nb + i];
        deg[i]   = cnt[nb + i];
        #pragma unroll
        for (int c = 0; c < 8; ++c) acc[i][c] = 0.f;
    }
    int dmax = max(deg[0], deg[1]);
    #pragma unroll
    for (int i = 0; i < 2; ++i)
        sv[i] = (lane < deg[i]) ? csr_src[start[i] + lane] : 0;

    #pragma unroll
    for (int cb = 0; cb < 64; cb += 16) {
        if (cb >= dmax) break;                 // wave-uniform
        int s00 = __shfl(sv[0], cb + g);
        int s01 = __shfl(sv[0], cb + 8 + g);
        int s10 = __shfl(sv[1], cb + g);
        int s11 = __shfl(sv[1], cb + 8 + g);
        uint4 v00 = *(const uint4*)(featb + s00 * 64 + cw);
        uint4 v01 = *(const uint4*)(featb + s01 * 64 + cw);
        uint4 v10 = *(const uint4*)(featb + s10 * 64 + cw);
        uint4 v11 = *(const uint4*)(featb + s11 * 64 + cw);
        int rem0 = deg[0] - cb;
        int rem1 = deg[1] - cb;
        upadd8(acc[0], v00, (g < rem0) ? 1.f : 0.f);
        upadd8(acc[0], v01, (g + 8 < rem0) ? 1.f : 0.f);
        upadd8(acc[1], v10, (g < rem1) ? 1.f : 0.f);
        upadd8(acc[1], v11, (g + 8 < rem1) ? 1.f : 0.f);
    }
    if (dmax > 64) {                           // rare tail (Poisson(16): ~never)
        for (int i = 0; i < 2; ++i) {
            for (int c0 = 64; c0 < deg[i]; c0 += 64) {
                int rem = deg[i] - c0; if (rem > 64) rem = 64;
                int sx = (lane < rem) ? csr_src[start[i] + c0 + lane] : 0;
                for (int cb = 0; cb < rem; cb += 16) {
                    int s0 = __shfl(sx, cb + g);
                    int s1 = __shfl(sx, cb + 8 + g);
                    float p0 = (cb + g < rem) ? 1.f : 0.f;
                    float p1 = (cb + 8 + g < rem) ? 1.f : 0.f;
                    uint4 v0 = *(const uint4*)(featb + s0 * 64 + cw);
                    uint4 v1 = *(const uint4*)(featb + s1 * 64 + cw);
                    upadd8(acc[i], v0, p0);
                    upadd8(acc[i], v1, p1);
                }
            }
        }
    }
    #pragma unroll
    for (int i = 0; i < 2; ++i) {
        float inv = 1.0f / fmaxf((float)deg[i], 1.0f);
        #pragma unroll
        for (int c = 0; c < 8; ++c) {
            float t = acc[i][c];
            t += __shfl_xor(t, 8);
            t += __shfl_xor(t, 16);
            t += __shfl_xor(t, 32);
            acc[i][c] = t * inv;
        }
    }
}

__device__ __forceinline__ float bf16u(unsigned short u) {
    return __uint_as_float(((unsigned)u) << 16);
}

// ---- 3. layer 1 (R2/R4/R9-proven): 2 nodes/wave; gather(xb) + W1 GEMM -> h1b ----
__global__ __launch_bounds__(256, 8) void layer1_fused(
    const unsigned short* __restrict__ xb,
    const int* __restrict__ csr_src, const int* __restrict__ row_start,
    const int* __restrict__ cnt, const float* __restrict__ W1,
    const float* __restrict__ b1, unsigned short* __restrict__ h1b) {
    int wv   = threadIdx.x >> 6;
    int lane = threadIdx.x & 63;
    int nb   = (blockIdx.x * 4 + wv) * 2;      // N_NODES % 8 == 0

    float acc[2][8];
    gather2(xb, csr_src, row_start, cnt, nb, lane, acc);

    __shared__ __align__(16) float selfF[4][2][64];
    __shared__ __align__(16) float meanF[4][2][64];
    #pragma unroll
    for (int i = 0; i < 2; ++i) {
        selfF[wv][i][lane] = bf16u(xb[((nb + i) << 6) + lane]);
        if (lane < 8) {
            *(float4*)&meanF[wv][i][lane * 8] =
                make_float4(acc[i][0], acc[i][1], acc[i][2], acc[i][3]);
            *(float4*)&meanF[wv][i][lane * 8 + 4] =
                make_float4(acc[i][4], acc[i][5], acc[i][6], acc[i][7]);
        }
    }
    WAVE_LDS_FENCE();

    float ao[2];
    float bb = b1[lane];
    #pragma unroll
    for (int i = 0; i < 2; ++i) ao[i] = bb;
    #pragma unroll
    for (int k = 0; k < IN_CH; ++k) {
        float w = W1[k * 64 + lane];           // lanes coalesced, reused x2
        #pragma unroll
        for (int i = 0; i < 2; ++i) ao[i] = fmaf(selfF[wv][i][k], w, ao[i]);
    }
    #pragma unroll
    for (int k = 0; k < IN_CH; ++k) {
        float w = W1[(IN_CH + k) * 64 + lane];
        #pragma unroll
        for (int i = 0; i < 2; ++i) ao[i] = fmaf(meanF[wv][i][k], w, ao[i]);
    }
    #pragma unroll
    for (int i = 0; i < 2; ++i) {
        float r = fmaxf(ao[i], 0.f);
        __hip_bfloat16 hb = __float2bfloat16(r);
        h1b[((nb + i) << 6) + lane] = *(unsigned short*)&hb;
    }
}

// ---- 3b. W2 pre-transform v2 (R5/R6-proven): 4 nodes/wave, all 64 lanes.
__global__ __launch_bounds__(256) void transform_w2(
    const unsigned short* __restrict__ h1b,
    const float* __restrict__ W2, const float* __restrict__ b2,
    unsigned short* __restrict__ y2b, float* __restrict__ yselff) {
    __shared__ __align__(16) float hrowF[4][4][64];    // 16KB: [wave][node][ch]
    int t    = threadIdx.x;
    int wv   = t >> 6;
    int lane = t & 63;
    int nb4  = blockIdx.x * 16 + wv * 4;               // grid*16 == N_NODES

    {
        int in = lane >> 4, q = lane & 15;
        uint2 hv = *(const uint2*)(h1b + (nb4 + in) * 64 + q * 4);
        float4 f;
        f.x = __uint_as_float(hv.x << 16);
        f.y = __uint_as_float(hv.x & 0xffff0000u);
        f.z = __uint_as_float(hv.y << 16);
        f.w = __uint_as_float(hv.y & 0xffff0000u);
        *(float4*)&hrowF[wv][in][q * 4] = f;
    }
    WAVE_LDS_FENCE();

    int jj  = lane & 31;
    int sel = lane >> 5;                               // 0: self (ys), 1: mean (ym)
    const float* Wp = W2 + sel * 64 * 32 + jj;
    float a[4] = {0.f, 0.f, 0.f, 0.f};
    #pragma unroll
    for (int k = 0; k < 64; ++k) {
        float w = Wp[k * 32];                          // 2 coalesced rows / wave
        #pragma unroll
        for (int i = 0; i < 4; ++i)
            a[i] = fmaf(hrowF[wv][i][k], w, a[i]);     // LDS broadcast
    }
    if (sel == 0) {
        float bb = b2[jj];
        #pragma unroll
        for (int i = 0; i < 4; ++i)
            yselff[(nb4 + i) * 32 + jj] = a[i] + bb;
    } else {
        #pragma unroll
        for (int i = 0; i < 4; ++i) {
            __hip_bfloat16 hb = __float2bfloat16(a[i]);
            y2b[(nb4 + i) * 32 + jj] = *(unsigned short*)&hb;
        }
    }
}

// ---- 4. layers 2+3 (exact R9 slim): gather y2b, mean, +yself, ReLU, dot W3.
__global__ __launch_bounds__(256, 8) void layer23_fused(
    const unsigned short* __restrict__ y2b,
    const int* __restrict__ csr_src, const int* __restrict__ row_start,
    const int* __restrict__ cnt, const float* __restrict__ yselff,
    const float* __restrict__ W3, const float* __restrict__ b3,
    float* __restrict__ out) {
    int wv   = threadIdx.x >> 6;
    int lane = threadIdx.x & 63;
    int nb   = (blockIdx.x * 4 + wv) * 2;
    int g  = lane >> 2;                        // 16 groups of 4 lanes
    int cw = (lane & 3) * 8;                   // bf16 offset within 32-ch row

    int start[2], deg[2], sv[2];
    float acc[2][8];
    #pragma unroll
    for (int i = 0; i < 2; ++i) {
        start[i] = row_start[nb + i];
        deg[i]   = cnt[nb + i];
        #pragma unroll
        for (int c = 0; c < 8; ++c) acc[i][c] = 0.f;
    }
    int dmax = max(deg[0], deg[1]);
    #pragma unroll
    for (int i = 0; i < 2; ++i)
        sv[i] = (lane < deg[i]) ? csr_src[start[i] + lane] : 0;

    #pragma unroll
    for (int cb = 0; cb < 64; cb += 32) {      // 32 neighbors per round trip
        if (cb >= dmax) break;                 // wave-uniform
        int s00 = __shfl(sv[0], cb + g);
        int s01 = __shfl(sv[0], cb + 16 + g);
        int s10 = __shfl(sv[1], cb + g);
        int s11 = __shfl(sv[1], cb + 16 + g);
        uint4 v00 = *(const uint4*)(y2b + s00 * 32 + cw);
        uint4 v01 = *(const uint4*)(y2b + s01 * 32 + cw);
        uint4 v10 = *(const uint4*)(y2b + s10 * 32 + cw);
        uint4 v11 = *(const uint4*)(y2b + s11 * 32 + cw);
        int rem0 = deg[0] - cb;
        int rem1 = deg[1] - cb;
        upadd8(acc[0], v00, (g < rem0) ? 1.f : 0.f);
        upadd8(acc[0], v01, (g + 16 < rem0) ? 1.f : 0.f);
        upadd8(acc[1], v10, (g < rem1) ? 1.f : 0.f);
        upadd8(acc[1], v11, (g + 16 < rem1) ? 1.f : 0.f);
    }
    if (dmax > 64) {                           // rare tail
        for (int i = 0; i < 2; ++i) {
            for (int c0 = 64; c0 < deg[i]; c0 += 64) {
                int rem = deg[i] - c0; if (rem > 64) rem = 64;
                int sx = (lane < rem) ? csr_src[start[i] + c0 + lane] : 0;
                for (int cb = 0; cb < rem; cb += 32) {
                    int s0 = __shfl(sx, cb + g);
                    int s1 = __shfl(sx, cb + 16 + g);
                    float p0 = (cb + g < rem) ? 1.f : 0.f;
                    float p1 = (cb + 16 + g < rem) ? 1.f : 0.f;
                    uint4 v0 = *(const uint4*)(y2b + s0 * 32 + cw);
                    uint4 v1 = *(const uint4*)(y2b + s1 * 32 + cw);
                    upadd8(acc[i], v0, p0);
                    upadd8(acc[i], v1, p1);
                }
            }
        }
    }

    // reduce across the 16 groups (lane bits 2..5), apply mean
    __shared__ __align__(16) float aggF[4][2][32];
    #pragma unroll
    for (int i = 0; i < 2; ++i) {
        float inv = 1.0f / fmaxf((float)deg[i], 1.0f);
        #pragma unroll
        for (int c = 0; c < 8; ++c) {
            float t = acc[i][c];
            t += __shfl_xor(t, 4);
            t += __shfl_xor(t, 8);
            t += __shfl_xor(t, 16);
            t += __shfl_xor(t, 32);
            acc[i][c] = t * inv;
        }
    }
    if (lane < 4) {
        #pragma unroll
        for (int i = 0; i < 2; ++i) {
            *(float4*)&aggF[wv][i][lane * 8] =
                make_float4(acc[i][0], acc[i][1], acc[i][2], acc[i][3]);
            *(float4*)&aggF[wv][i][lane * 8 + 4] =
                make_float4(acc[i][4], acc[i][5], acc[i][6], acc[i][7]);
        }
    }
    WAVE_LDS_FENCE();

    int hh = lane >> 5;                        // half-wave id: node nb+hh
    int j  = lane & 31;
    float pre = yselff[(nb + hh) * 32 + j] + aggF[wv][hh][j];
    float v0 = fmaxf(pre, 0.f) * W3[j];
    #pragma unroll
    for (int off = 1; off <= 16; off <<= 1)
        v0 += __shfl_xor(v0, off);
    if (j == 0)
        out[nb + hh] = v0 + b3[0];
}

extern "C" void kernel_launch(void* const* d_in, const int* in_sizes, int n_in,
                              void* d_out, int out_size, void* d_ws, size_t ws_size,
                              hipStream_t stream) {
    const float* x   = (const float*)d_in[0];
    const int*   ei  = (const int*)d_in[1];
    const int*   src = ei;
    const int*   dst = ei + N_EDGES;
    const float* W1  = (const float*)d_in[2];
    const float* b1  = (const float*)d_in[3];
    const float* W2  = (const float*)d_in[4];
    const float* b2  = (const float*)d_in[5];
    const float* W3  = (const float*)d_in[6];
    const float* b3  = (const float*)d_in[7];
    float* out = (float*)d_out;

    // ws (~78 MB): cursor_rel[512] | cnt | row_start | binned 12.8MB | csr_src 12.8MB |
    //   xb bf16 12.8MB | h1b bf16 12.8MB | y2b bf16 6.4MB | yselff fp32 12.8MB
    char* ws = (char*)d_ws;
    auto align = [](size_t v) { return (v + 255) & ~(size_t)255; };
    size_t o = 0;
    int* cursor_rel = (int*)(ws + o); o = align(o + 512 * 4);
    int* cnt       = (int*)(ws + o); o = align(o + (size_t)N_NODES * 4);
    int* row_start = (int*)(ws + o); o = align(o + (size_t)N_NODES * 4);
    unsigned* binned = (unsigned*)(ws + o); o = align(o + ((size_t)NB << CAPLOG) * 4);
    int* csr_src   = (int*)(ws + o); o = align(o + ((size_t)NB << CAPLOG) * 4);
    unsigned short* xb  = (unsigned short*)(ws + o); o = align(o + (size_t)N_NODES * 64 * 2);
    unsigned short* h1b = (unsigned short*)(ws + o); o = align(o + (size_t)N_NODES * 64 * 2);
    unsigned short* y2b = (unsigned short*)(ws + o); o = align(o + (size_t)N_NODES * 32 * 2);
    float* yselff = (float*)(ws + o); o = align(o + (size_t)N_NODES * 32 * 4);

    (void)hipMemsetAsync(cursor_rel, 0, 512 * sizeof(int), stream);

    bin_pad_kernel<<<NBLK_A + PAD_BLOCKS, 1024, 0, stream>>>(src, dst, cursor_rel,
                                                             binned, x, xb);
    bucket_fine<<<NB, 1024, 0, stream>>>(binned, cursor_rel, cnt, row_start, csr_src);

    layer1_fused<<<N_NODES / 8, 256, 0, stream>>>(xb, csr_src, row_start, cnt,
                                                  W1, b1, h1b);
    transform_w2<<<N_NODES / 16, 256, 0, stream>>>(h1b, W2, b2, y2b, yselff);
    layer23_fused<<<N_NODES / 8, 256, 0, stream>>>(y2b, csr_src, row_start, cnt,
                                                   yselff, W3, b3, out);
}

// Round 13
// 224.589 us; speedup vs baseline: 1.2621x; 1.0011x over previous
//
#include <hip/hip_runtime.h>
#include <hip/hip_bf16.h>

#define N_NODES 100000
#define N_EDGES 1600000
#define IN_CH 50
#define NPB 256                                   // nodes per bucket (dst >> 8)
#define NB ((N_NODES + NPB - 1) / NPB)            // 391 buckets
#define CAPLOG 13                                 // 8192 slots/bucket (max ~4.5K used)
#define EPB 8192                                  // edges per bin block (8/thread)
#define NBLK_A ((N_EDGES + EPB - 1) / EPB)        // 196 bin blocks
#define PAD_BLOCKS ((N_NODES * 16 + 1023) / 1024) // 1563 pad blocks (4ch/thread)

__device__ __forceinline__ unsigned pack2bf(float a, float b) {
    __hip_bfloat16 lo = __float2bfloat16(a);
    __hip_bfloat16 hi = __float2bfloat16(b);
    return ((unsigned)*(unsigned short*)&hi << 16) | *(unsigned short*)&lo;
}

// ---- 1. bin edges into fixed-capacity buckets (+ extra blocks: pad x->xb bf16) ----
// R9-proven rank-from-count; pad lane 4 channels/thread (uint2 writes, R12-proven).
__global__ __launch_bounds__(1024) void bin_pad_kernel(
    const int* __restrict__ src, const int* __restrict__ dst,
    int* __restrict__ cursor_rel, unsigned* __restrict__ binned,
    const float* __restrict__ x, unsigned short* __restrict__ xb) {
    if (blockIdx.x >= NBLK_A) {                    // pad lane
        int t = (blockIdx.x - NBLK_A) * 1024 + threadIdx.x;
        if (t >= N_NODES * 16) return;
        int n = t >> 4, q = t & 15;                // q = 4-channel group
        unsigned lo = 0, hi = 0;
        if (q < 12) {
            float2 v0 = *(const float2*)(x + n * IN_CH + q * 4);
            float2 v1 = *(const float2*)(x + n * IN_CH + q * 4 + 2);
            lo = pack2bf(v0.x, v0.y);
            hi = pack2bf(v1.x, v1.y);
        } else if (q == 12) {                      // ch 48,49 live; 50,51 zero
            float2 v0 = *(const float2*)(x + n * IN_CH + 48);
            lo = pack2bf(v0.x, v0.y);
        }
        *(uint2*)(xb + n * 64 + q * 4) = make_uint2(lo, hi);
        return;
    }
    __shared__ int bc[NB];
    __shared__ int boff[NB];
    int t = threadIdx.x;
    if (t < NB) bc[t] = 0;
    __syncthreads();
    int e0 = blockIdx.x * EPB;
    int ne = min(e0 + EPB, N_EDGES) - e0;
    unsigned payl[8];
    int bkt[8], rnk[8];
    #pragma unroll
    for (int r = 0; r < 8; ++r) {
        int i = t + r * 1024;
        if (i < ne) {
            int d = dst[e0 + i];
            payl[r] = ((unsigned)(d & 255) << 17) | (unsigned)src[e0 + i];
            bkt[r]  = d >> 8;
            rnk[r]  = atomicAdd(&bc[bkt[r]], 1);   // rank within bucket, this block
        }
    }
    __syncthreads();
    if (t < NB) {
        int v = bc[t];
        int rel = v ? atomicAdd(&cursor_rel[t], v) : 0;
        boff[t] = (t << CAPLOG) + rel;
    }
    __syncthreads();
    #pragma unroll
    for (int r = 0; r < 8; ++r) {
        int i = t + r * 1024;
        if (i < ne)
            binned[boff[bkt[r]] + rnk[r]] = payl[r];
    }
}

// ---- 2. per-bucket fine sort -> cnt, row_start, csr_src ----
// R13: 512 threads (was 1024). 16-wave blocks paid ~500cyc x 18 __syncthreads
// (Hillis-Steele scan) and serialized at 1.5 blocks/CU; 8-wave blocks halve
// barrier cost and fit 4/CU (35KB LDS) -> all 391 blocks co-resident.
// Staging depth 8->12 (12*512=6144 >= max bucket ~4.5K, +32 sigma margin).
__global__ __launch_bounds__(512) void bucket_fine(
    const unsigned* __restrict__ binned, const int* __restrict__ cursor_rel,
    int* __restrict__ cnt, int* __restrict__ row_start, int* __restrict__ csr_src) {
    __shared__ unsigned srt[1 << CAPLOG];          // 32KB
    __shared__ int lcnt[NPB];
    __shared__ int lofs[NPB];
    __shared__ int sc[NPB];
    int t = threadIdx.x;
    int b = blockIdx.x;
    int nbase = b * NPB;
    int bbase = b << CAPLOG;
    int ecnt  = cursor_rel[b];
    if (t < NPB) lcnt[t] = 0;
    __syncthreads();
    unsigned pay[12];
    int rnk[12];
    #pragma unroll
    for (int r = 0; r < 12; ++r) {
        int i = t + r * 512;
        if (i < ecnt) {
            pay[r] = binned[bbase + i];
            rnk[r] = atomicAdd(&lcnt[(pay[r] >> 17) & 255], 1);
        }
    }
    __syncthreads();
    int v = (t < NPB) ? lcnt[t] : 0;
    if (t < NPB) sc[t] = v;
    __syncthreads();
    for (int off = 1; off < NPB; off <<= 1) {      // Hillis-Steele over 256
        int tmp = (t < NPB && t >= off) ? sc[t - off] : 0;
        __syncthreads();
        if (t < NPB) sc[t] += tmp;
        __syncthreads();
    }
    if (t < NPB) {
        int excl = sc[t] - v;
        lofs[t] = excl;
        int n = nbase + t;
        if (n < N_NODES) { cnt[n] = v; row_start[n] = bbase + excl; }
    }
    __syncthreads();
    #pragma unroll
    for (int r = 0; r < 12; ++r) {
        int i = t + r * 512;
        if (i < ecnt)
            srt[lofs[(pay[r] >> 17) & 255] + rnk[r]] = pay[r] & 0x1FFFFu;
    }
    __syncthreads();
    for (int i = t; i < ecnt; i += 512)
        csr_src[bbase + i] = (int)srt[i];          // coalesced
}

// unpack 8 bf16 from uint4, predicated fma into acc[0..8)
__device__ __forceinline__ void upadd8(float* a, uint4 v, float p) {
    a[0] = fmaf(p, __uint_as_float(v.x << 16), a[0]);
    a[1] = fmaf(p, __uint_as_float(v.x & 0xffff0000u), a[1]);
    a[2] = fmaf(p, __uint_as_float(v.y << 16), a[2]);
    a[3] = fmaf(p, __uint_as_float(v.y & 0xffff0000u), a[3]);
    a[4] = fmaf(p, __uint_as_float(v.z << 16), a[4]);
    a[5] = fmaf(p, __uint_as_float(v.z & 0xffff0000u), a[5]);
    a[6] = fmaf(p, __uint_as_float(v.w << 16), a[6]);
    a[7] = fmaf(p, __uint_as_float(v.w & 0xffff0000u), a[7]);
}

// wave-local LDS fence: LDS ops of one wave complete in order; no block barrier.
#define WAVE_LDS_FENCE() __asm__ volatile("s_waitcnt lgkmcnt(0)" ::: "memory")

// Gather-mean of 2 nodes per wave (exact R9: unconditional loads — R10's
// conditional uint4 assignment spilled to scratch, +137MB HBM writes).
__device__ __forceinline__ void gather2(
    const unsigned short* __restrict__ featb, const int* __restrict__ csr_src,
    const int* __restrict__ row_start, const int* __restrict__ cnt,
    int nb, int lane, float acc[2][8]) {
    int g  = lane >> 3;
    int cw = (lane & 7) * 8;
    int start[2], deg[2], sv[2];
    #pragma unroll
    for (int i = 0; i < 2; ++i) {
        start[i] = row_start[nb + i];
        deg[i]   = cnt[nb + i];
        #pragma unroll
        for (int c = 0; c < 8; ++c) acc[i][c] = 0.f;
    }
    int dmax = max(deg[0], deg[1]);
    #pragma unroll
    for (int i = 0; i < 2; ++i)
        sv[i] = (lane < deg[i]) ? csr_src[start[i] + lane] : 0;

    #pragma unroll
    for (int cb = 0; cb < 64; cb += 16) {
        if (cb >= dmax) break;                 // wave-uniform
        int s00 = __shfl(sv[0], cb + g);
        int s01 = __shfl(sv[0], cb + 8 + g);
        int s10 = __shfl(sv[1], cb + g);
        int s11 = __shfl(sv[1], cb + 8 + g);
        uint4 v00 = *(const uint4*)(featb + s00 * 64 + cw);
        uint4 v01 = *(const uint4*)(featb + s01 * 64 + cw);
        uint4 v10 = *(const uint4*)(featb + s10 * 64 + cw);
        uint4 v11 = *(const uint4*)(featb + s11 * 64 + cw);
        int rem0 = deg[0] - cb;
        int rem1 = deg[1] - cb;
        upadd8(acc[0], v00, (g < rem0) ? 1.f : 0.f);
        upadd8(acc[0], v01, (g + 8 < rem0) ? 1.f : 0.f);
        upadd8(acc[1], v10, (g < rem1) ? 1.f : 0.f);
        upadd8(acc[1], v11, (g + 8 < rem1) ? 1.f : 0.f);
    }
    if (dmax > 64) {                           // rare tail (Poisson(16): ~never)
        for (int i = 0; i < 2; ++i) {
            for (int c0 = 64; c0 < deg[i]; c0 += 64) {
                int rem = deg[i] - c0; if (rem > 64) rem = 64;
                int sx = (lane < rem) ? csr_src[start[i] + c0 + lane] : 0;
                for (int cb = 0; cb < rem; cb += 16) {
                    int s0 = __shfl(sx, cb + g);
                    int s1 = __shfl(sx, cb + 8 + g);
                    float p0 = (cb + g < rem) ? 1.f : 0.f;
                    float p1 = (cb + 8 + g < rem) ? 1.f : 0.f;
                    uint4 v0 = *(const uint4*)(featb + s0 * 64 + cw);
                    uint4 v1 = *(const uint4*)(featb + s1 * 64 + cw);
                    upadd8(acc[i], v0, p0);
                    upadd8(acc[i], v1, p1);
                }
            }
        }
    }
    #pragma unroll
    for (int i = 0; i < 2; ++i) {
        float inv = 1.0f / fmaxf((float)deg[i], 1.0f);
        #pragma unroll
        for (int c = 0; c < 8; ++c) {
            float t = acc[i][c];
            t += __shfl_xor(t, 8);
            t += __shfl_xor(t, 16);
            t += __shfl_xor(t, 32);
            acc[i][c] = t * inv;
        }
    }
}

__device__ __forceinline__ float bf16u(unsigned short u) {
    return __uint_as_float(((unsigned)u) << 16);
}

// ---- 3. layer 1 (R2/R4/R9-proven): 2 nodes/wave; gather(xb) + W1 GEMM -> h1b ----
__global__ __launch_bounds__(256, 8) void layer1_fused(
    const unsigned short* __restrict__ xb,
    const int* __restrict__ csr_src, const int* __restrict__ row_start,
    const int* __restrict__ cnt, const float* __restrict__ W1,
    const float* __restrict__ b1, unsigned short* __restrict__ h1b) {
    int wv   = threadIdx.x >> 6;
    int lane = threadIdx.x & 63;
    int nb   = (blockIdx.x * 4 + wv) * 2;      // N_NODES % 8 == 0

    float acc[2][8];
    gather2(xb, csr_src, row_start, cnt, nb, lane, acc);

    __shared__ __align__(16) float selfF[4][2][64];
    __shared__ __align__(16) float meanF[4][2][64];
    #pragma unroll
    for (int i = 0; i < 2; ++i) {
        selfF[wv][i][lane] = bf16u(xb[((nb + i) << 6) + lane]);
        if (lane < 8) {
            *(float4*)&meanF[wv][i][lane * 8] =
                make_float4(acc[i][0], acc[i][1], acc[i][2], acc[i][3]);
            *(float4*)&meanF[wv][i][lane * 8 + 4] =
                make_float4(acc[i][4], acc[i][5], acc[i][6], acc[i][7]);
        }
    }
    WAVE_LDS_FENCE();

    float ao[2];
    float bb = b1[lane];
    #pragma unroll
    for (int i = 0; i < 2; ++i) ao[i] = bb;
    #pragma unroll
    for (int k = 0; k < IN_CH; ++k) {
        float w = W1[k * 64 + lane];           // lanes coalesced, reused x2
        #pragma unroll
        for (int i = 0; i < 2; ++i) ao[i] = fmaf(selfF[wv][i][k], w, ao[i]);
    }
    #pragma unroll
    for (int k = 0; k < IN_CH; ++k) {
        float w = W1[(IN_CH + k) * 64 + lane];
        #pragma unroll
        for (int i = 0; i < 2; ++i) ao[i] = fmaf(meanF[wv][i][k], w, ao[i]);
    }
    #pragma unroll
    for (int i = 0; i < 2; ++i) {
        float r = fmaxf(ao[i], 0.f);
        __hip_bfloat16 hb = __float2bfloat16(r);
        h1b[((nb + i) << 6) + lane] = *(unsigned short*)&hb;
    }
}

// ---- 3b. W2 pre-transform v2 (R5/R6-proven): 4 nodes/wave, all 64 lanes.
__global__ __launch_bounds__(256) void transform_w2(
    const unsigned short* __restrict__ h1b,
    const float* __restrict__ W2, const float* __restrict__ b2,
    unsigned short* __restrict__ y2b, float* __restrict__ yselff) {
    __shared__ __align__(16) float hrowF[4][4][64];    // 16KB: [wave][node][ch]
    int t    = threadIdx.x;
    int wv   = t >> 6;
    int lane = t & 63;
    int nb4  = blockIdx.x * 16 + wv * 4;               // grid*16 == N_NODES

    {
        int in = lane >> 4, q = lane & 15;
        uint2 hv = *(const uint2*)(h1b + (nb4 + in) * 64 + q * 4);
        float4 f;
        f.x = __uint_as_float(hv.x << 16);
        f.y = __uint_as_float(hv.x & 0xffff0000u);
        f.z = __uint_as_float(hv.y << 16);
        f.w = __uint_as_float(hv.y & 0xffff0000u);
        *(float4*)&hrowF[wv][in][q * 4] = f;
    }
    WAVE_LDS_FENCE();

    int jj  = lane & 31;
    int sel = lane >> 5;                               // 0: self (ys), 1: mean (ym)
    const float* Wp = W2 + sel * 64 * 32 + jj;
    float a[4] = {0.f, 0.f, 0.f, 0.f};
    #pragma unroll
    for (int k = 0; k < 64; ++k) {
        float w = Wp[k * 32];                          // 2 coalesced rows / wave
        #pragma unroll
        for (int i = 0; i < 4; ++i)
            a[i] = fmaf(hrowF[wv][i][k], w, a[i]);     // LDS broadcast
    }
    if (sel == 0) {
        float bb = b2[jj];
        #pragma unroll
        for (int i = 0; i < 4; ++i)
            yselff[(nb4 + i) * 32 + jj] = a[i] + bb;
    } else {
        #pragma unroll
        for (int i = 0; i < 4; ++i) {
            __hip_bfloat16 hb = __float2bfloat16(a[i]);
            y2b[(nb4 + i) * 32 + jj] = *(unsigned short*)&hb;
        }
    }
}

// ---- 4. layers 2+3 (exact R9 slim): gather y2b, mean, +yself, ReLU, dot W3.
__global__ __launch_bounds__(256, 8) void layer23_fused(
    const unsigned short* __restrict__ y2b,
    const int* __restrict__ csr_src, const int* __restrict__ row_start,
    const int* __restrict__ cnt, const float* __restrict__ yselff,
    const float* __restrict__ W3, const float* __restrict__ b3,
    float* __restrict__ out) {
    int wv   = threadIdx.x >> 6;
    int lane = threadIdx.x & 63;
    int nb   = (blockIdx.x * 4 + wv) * 2;
    int g  = lane >> 2;                        // 16 groups of 4 lanes
    int cw = (lane & 3) * 8;                   // bf16 offset within 32-ch row

    int start[2], deg[2], sv[2];
    float acc[2][8];
    #pragma unroll
    for (int i = 0; i < 2; ++i) {
        start[i] = row_start[nb + i];
        deg[i]   = cnt[nb + i];
        #pragma unroll
        for (int c = 0; c < 8; ++c) acc[i][c] = 0.f;
    }
    int dmax = max(deg[0], deg[1]);
    #pragma unroll
    for (int i = 0; i < 2; ++i)
        sv[i] = (lane < deg[i]) ? csr_src[start[i] + lane] : 0;

    #pragma unroll
    for (int cb = 0; cb < 64; cb += 32) {      // 32 neighbors per round trip
        if (cb >= dmax) break;                 // wave-uniform
        int s00 = __shfl(sv[0], cb + g);
        int s01 = __shfl(sv[0], cb + 16 + g);
        int s10 = __shfl(sv[1], cb + g);
        int s11 = __shfl(sv[1], cb + 16 + g);
        uint4 v00 = *(const uint4*)(y2b + s00 * 32 + cw);
        uint4 v01 = *(const uint4*)(y2b + s01 * 32 + cw);
        uint4 v10 = *(const uint4*)(y2b + s10 * 32 + cw);
        uint4 v11 = *(const uint4*)(y2b + s11 * 32 + cw);
        int rem0 = deg[0] - cb;
        int rem1 = deg[1] - cb;
        upadd8(acc[0], v00, (g < rem0) ? 1.f : 0.f);
        upadd8(acc[0], v01, (g + 16 < rem0) ? 1.f : 0.f);
        upadd8(acc[1], v10, (g < rem1) ? 1.f : 0.f);
        upadd8(acc[1], v11, (g + 16 < rem1) ? 1.f : 0.f);
    }
    if (dmax > 64) {                           // rare tail
        for (int i = 0; i < 2; ++i) {
            for (int c0 = 64; c0 < deg[i]; c0 += 64) {
                int rem = deg[i] - c0; if (rem > 64) rem = 64;
                int sx = (lane < rem) ? csr_src[start[i] + c0 + lane] : 0;
                for (int cb = 0; cb < rem; cb += 32) {
                    int s0 = __shfl(sx, cb + g);
                    int s1 = __shfl(sx, cb + 16 + g);
                    float p0 = (cb + g < rem) ? 1.f : 0.f;
                    float p1 = (cb + 16 + g < rem) ? 1.f : 0.f;
                    uint4 v0 = *(const uint4*)(y2b + s0 * 32 + cw);
                    uint4 v1 = *(const uint4*)(y2b + s1 * 32 + cw);
                    upadd8(acc[i], v0, p0);
                    upadd8(acc[i], v1, p1);
                }
            }
        }
    }

    // reduce across the 16 groups (lane bits 2..5), apply mean
    __shared__ __align__(16) float aggF[4][2][32];
    #pragma unroll
    for (int i = 0; i < 2; ++i) {
        float inv = 1.0f / fmaxf((float)deg[i], 1.0f);
        #pragma unroll
        for (int c = 0; c < 8; ++c) {
            float t = acc[i][c];
            t += __shfl_xor(t, 4);
            t += __shfl_xor(t, 8);
            t += __shfl_xor(t, 16);
            t += __shfl_xor(t, 32);
            acc[i][c] = t * inv;
        }
    }
    if (lane < 4) {
        #pragma unroll
        for (int i = 0; i < 2; ++i) {
            *(float4*)&aggF[wv][i][lane * 8] =
                make_float4(acc[i][0], acc[i][1], acc[i][2], acc[i][3]);
            *(float4*)&aggF[wv][i][lane * 8 + 4] =
                make_float4(acc[i][4], acc[i][5], acc[i][6], acc[i][7]);
        }
    }
    WAVE_LDS_FENCE();

    int hh = lane >> 5;                        // half-wave id: node nb+hh
    int j  = lane & 31;
    float pre = yselff[(nb + hh) * 32 + j] + aggF[wv][hh][j];
    float v0 = fmaxf(pre, 0.f) * W3[j];
    #pragma unroll
    for (int off = 1; off <= 16; off <<= 1)
        v0 += __shfl_xor(v0, off);
    if (j == 0)
        out[nb + hh] = v0 + b3[0];
}

extern "C" void kernel_launch(void* const* d_in, const int* in_sizes, int n_in,
                              void* d_out, int out_size, void* d_ws, size_t ws_size,
                              hipStream_t stream) {
    const float* x   = (const float*)d_in[0];
    const int*   ei  = (const int*)d_in[1];
    const int*   src = ei;
    const int*   dst = ei + N_EDGES;
    const float* W1  = (const float*)d_in[2];
    const float* b1  = (const float*)d_in[3];
    const float* W2  = (const float*)d_in[4];
    const float* b2  = (const float*)d_in[5];
    const float* W3  = (const float*)d_in[6];
    const float* b3  = (const float*)d_in[7];
    float* out = (float*)d_out;

    // ws (~78 MB): cursor_rel[512] | cnt | row_start | binned 12.8MB | csr_src 12.8MB |
    //   xb bf16 12.8MB | h1b bf16 12.8MB | y2b bf16 6.4MB | yselff fp32 12.8MB
    char* ws = (char*)d_ws;
    auto align = [](size_t v) { return (v + 255) & ~(size_t)255; };
    size_t o = 0;
    int* cursor_rel = (int*)(ws + o); o = align(o + 512 * 4);
    int* cnt       = (int*)(ws + o); o = align(o + (size_t)N_NODES * 4);
    int* row_start = (int*)(ws + o); o = align(o + (size_t)N_NODES * 4);
    unsigned* binned = (unsigned*)(ws + o); o = align(o + ((size_t)NB << CAPLOG) * 4);
    int* csr_src   = (int*)(ws + o); o = align(o + ((size_t)NB << CAPLOG) * 4);
    unsigned short* xb  = (unsigned short*)(ws + o); o = align(o + (size_t)N_NODES * 64 * 2);
    unsigned short* h1b = (unsigned short*)(ws + o); o = align(o + (size_t)N_NODES * 64 * 2);
    unsigned short* y2b = (unsigned short*)(ws + o); o = align(o + (size_t)N_NODES * 32 * 2);
    float* yselff = (float*)(ws + o); o = align(o + (size_t)N_NODES * 32 * 4);

    (void)hipMemsetAsync(cursor_rel, 0, 512 * sizeof(int), stream);

    bin_pad_kernel<<<NBLK_A + PAD_BLOCKS, 1024, 0, stream>>>(src, dst, cursor_rel,
                                                             binned, x, xb);
    bucket_fine<<<NB, 512, 0, stream>>>(binned, cursor_rel, cnt, row_start, csr_src);

    layer1_fused<<<N_NODES / 8, 256, 0, stream>>>(xb, csr_src, row_start, cnt,
                                                  W1, b1, h1b);
    transform_w2<<<N_NODES / 16, 256, 0, stream>>>(h1b, W2, b2, y2b, yselff);
    layer23_fused<<<N_NODES / 8, 256, 0, stream>>>(y2b, csr_src, row_start, cnt,
                                                   yselff, W3, b3, out);
}